// Round 4
// baseline (153.896 us; speedup 1.0000x reference)
//
#include <hip/hip_runtime.h>
#include <hip/hip_bf16.h>

#define RADIUS_F 1.3f
#define NSAMP 767
#define STEPF 0.01015625f   // RADIUS*2/COARSE/FINE/2
#define BATCH 1024

typedef __attribute__((ext_vector_type(8))) short short8;
typedef __attribute__((ext_vector_type(4))) float floatx4;
typedef __attribute__((ext_vector_type(2))) float floatx2;

static __device__ __forceinline__ unsigned pkbf(float a, float b) {
    union { __hip_bfloat162 h; unsigned u; } cvt;
    cvt.h = __float22bfloat162_rn(make_float2(a, b));
    return cvt.u;
}

__launch_bounds__(256, 2)
__global__ void plenoxels_fwd(const float* __restrict__ rays_o,
                              const float* __restrict__ rays_d,
                              const float* __restrict__ grid,
                              const float* __restrict__ atoms,
                              float* __restrict__ out)
{
    // LDS: 4096 (B', 4 rows only) + 1536 (alpha) + 4608 (rgb) = 10240 B
    __shared__ __align__(16) __hip_bfloat16 BpL[4 * 512];   // B'[c][p] bf16, frag-order permuted
    __shared__ __align__(16) __hip_bfloat16 alphaL[768];
    __shared__ __align__(16) __hip_bfloat16 rgbL[768 * 3];

    const int tid  = threadIdx.x;
    const int ray  = blockIdx.x;
    const int lane = tid & 63;
    const int w    = tid >> 6;
    const int m    = lane & 15;   // A row (sample-in-tile) / B col / C col
    const int quad = lane >> 4;

    // ---- per-ray constants (redundant per thread) ----
    const float ox = rays_o[ray * 3 + 0], oy = rays_o[ray * 3 + 1], oz = rays_o[ray * 3 + 2];
    const float dx = rays_d[ray * 3 + 0], dy = rays_d[ray * 3 + 1], dz = rays_d[ray * 3 + 2];

    float start;
    {
        float a0 = (RADIUS_F - ox) / dx, b0 = (-RADIUS_F - ox) / dx;
        float a1 = (RADIUS_F - oy) / dy, b1 = (-RADIUS_F - oy) / dy;
        float a2 = (RADIUS_F - oz) / dz, b2 = (-RADIUS_F - oz) / dz;
        start = fmaxf(fminf(a0, b0), fmaxf(fminf(a1, b1), fminf(a2, b2)));
    }
    const float dnorm = sqrtf(dx * dx + dy * dy + dz * dz);
    const float dist = STEPF * dnorm;

    float shm[9];
    {
        float inv = 1.0f / dnorm;
        float nx = dx * inv, ny = dy * inv, nz = dz * inv;
        shm[0] = 0.28209479177387814f;
        shm[1] = -0.4886025119029199f * ny;
        shm[2] = 0.4886025119029199f * nz;
        shm[3] = -0.4886025119029199f * nx;
        shm[4] = 1.0925484305920792f * nx * ny;
        shm[5] = -1.0925484305920792f * ny * nz;
        shm[6] = 0.31539156525252005f * (2.f * nz * nz - nx * nx - ny * ny);
        shm[7] = -1.0925484305920792f * nx * nz;
        shm[8] = 0.5462742152960396f * (nx * nx - ny * ny);
    }

    // ---- build B' (atoms pre-contracted with SH), stored in MFMA-frag order:
    //      frag step ks consumes a = 16*quad + ks, f = j
    //      position p(a,f) = (a&15)*32 + (a>>4)*8 + f
    for (int k = tid; k < 512; k += 256) {
        int f = k & 7, a = k >> 3;
        int p = ((a & 15) << 5) + ((a >> 4) << 3) + f;
        const float* base = atoms + (f * 64 + a) * 28;
        float s0 = 0.f, s1 = 0.f, s2 = 0.f;
        #pragma unroll
        for (int i = 0; i < 9; ++i) {
            s0 = fmaf(base[i],      shm[i], s0);
            s1 = fmaf(base[9 + i],  shm[i], s1);
            s2 = fmaf(base[18 + i], shm[i], s2);
        }
        BpL[0 * 512 + p] = __float2bfloat16(s0);
        BpL[1 * 512 + p] = __float2bfloat16(s1);
        BpL[2 * 512 + p] = __float2bfloat16(s2);
        BpL[3 * 512 + p] = __float2bfloat16(base[27]);   // sigma column
    }
    __syncthreads();

    // ---- B'-fragments: lanes m<4 read their column; m>=4 hold zeros ----
    short8 bfr[16];
    {
        short8 z = {0, 0, 0, 0, 0, 0, 0, 0};
        #pragma unroll
        for (int ks = 0; ks < 16; ++ks) bfr[ks] = z;
        if (m < 4) {
            const short* bs = (const short*)BpL;
            #pragma unroll
            for (int ks = 0; ks < 16; ++ks)
                bfr[ks] = *(const short8*)(bs + m * 512 + ks * 32 + quad * 8);
        }
    }

    float* out_rgb   = out;
    float* out_alpha = out + BATCH * 3;
    float* out_depth = out + BATCH * 3 + BATCH * NSAMP;
    const float4* g4 = (const float4*)grid;

    // geometry + trilinear fine weights
    auto geom = [&](int s, float W[8], int& clin) -> int {
        float tr = start + (float)s * STEPF;
        float px = ox + tr * dx, py = oy + tr * dy, pz = oz + tr * dz;
        int mask = (px > -RADIUS_F) & (px < RADIUS_F) &
                   (py > -RADIUS_F) & (py < RADIUS_F) &
                   (pz > -RADIUS_F) & (pz < RADIUS_F);
        const float sc = 1.0f / (2.0f * RADIUS_F);
        float qx = fminf(fmaxf((px + RADIUS_F) * sc, 0.f), 1.0f - 1e-6f);
        float qy = fminf(fmaxf((py + RADIUS_F) * sc, 0.f), 1.0f - 1e-6f);
        float qz = fminf(fmaxf((pz + RADIUS_F) * sc, 0.f), 1.0f - 1e-6f);
        float pcx = qx * 64.f, pcy = qy * 64.f, pcz = qz * 64.f;
        float cx = fminf(floorf(pcx), 63.f);
        float cy = fminf(floorf(pcy), 63.f);
        float cz = fminf(floorf(pcz), 63.f);
        float lx = pcx - cx, ly = pcy - cy, lz = pcz - cz;
        clin = (((int)cx * 64) + (int)cy) * 64 + (int)cz;
        float xw0, xw1, yw0, yw1, zw0, zw1;
        {
            float u = lx * 2.f - 0.5f, fF = floorf(u), t = u - fF;
            xw0 = (fF < 0.f) ? 1.f : ((fF > 0.f) ? 0.f : 1.f - t);
            xw1 = (fF < 0.f) ? 0.f : ((fF > 0.f) ? 1.f : t);
        }
        {
            float u = ly * 2.f - 0.5f, fF = floorf(u), t = u - fF;
            yw0 = (fF < 0.f) ? 1.f : ((fF > 0.f) ? 0.f : 1.f - t);
            yw1 = (fF < 0.f) ? 0.f : ((fF > 0.f) ? 1.f : t);
        }
        {
            float u = lz * 2.f - 0.5f, fF = floorf(u), t = u - fF;
            zw0 = (fF < 0.f) ? 1.f : ((fF > 0.f) ? 0.f : 1.f - t);
            zw1 = (fF < 0.f) ? 0.f : ((fF > 0.f) ? 1.f : t);
        }
        W[0] = xw0 * yw0 * zw0; W[1] = xw0 * yw0 * zw1;
        W[2] = xw0 * yw1 * zw0; W[3] = xw0 * yw1 * zw1;
        W[4] = xw1 * yw0 * zw0; W[5] = xw1 * yw0 * zw1;
        W[6] = xw1 * yw1 * zw0; W[7] = xw1 * yw1 * zw1;
        return mask;
    };

    // ---- software-pipelined tile loop: coeff quarters live in registers ----
    float Wc[8]; int clinC; int maskC;
    maskC = geom(w * 192 + m, Wc, clinC);
    float4 cv[4];
    {
        const float4* gp = g4 + (clinC << 4) + (quad << 2);
        cv[0] = gp[0]; cv[1] = gp[1]; cv[2] = gp[2]; cv[3] = gp[3];
    }

    for (int t = 0; t < 12; ++t) {
        const int tile = w * 12 + t;

        float4 cu[4];
        #pragma unroll
        for (int j = 0; j < 4; ++j) cu[j] = cv[j];
        floatx2 W01 = {Wc[0], Wc[1]}, W23 = {Wc[2], Wc[3]};
        floatx2 W45 = {Wc[4], Wc[5]}, W67 = {Wc[6], Wc[7]};
        const int maskS = maskC;

        // prefetch next tile's geometry + coeff gather (hides L2 latency)
        if (t < 11) {
            maskC = geom(w * 192 + (t + 1) * 16 + m, Wc, clinC);
            const float4* gp = g4 + (clinC << 4) + (quad << 2);
            cv[0] = gp[0]; cv[1] = gp[1]; cv[2] = gp[2]; cv[3] = gp[3];
        }

        // K-loop: step ks uses coeff a = 16*quad + ks == this lane's own loads
        floatx4 acc = {0.f, 0.f, 0.f, 0.f};
        #pragma unroll
        for (int ks = 0; ks < 16; ++ks) {
            const float4& q4v = cu[ks >> 2];
            float cr = (ks & 3) == 0 ? q4v.x : (ks & 3) == 1 ? q4v.y
                     : (ks & 3) == 2 ? q4v.z : q4v.w;
            floatx2 p0 = W01 * cr, p1 = W23 * cr, p2 = W45 * cr, p3 = W67 * cr;
            union { unsigned u[4]; short8 s; } af;
            af.u[0] = pkbf(p0.x, p0.y);
            af.u[1] = pkbf(p1.x, p1.y);
            af.u[2] = pkbf(p2.x, p2.y);
            af.u[3] = pkbf(p3.x, p3.y);
            acc = __builtin_amdgcn_mfma_f32_16x16x32_bf16(af.s, bfr[ks], acc, 0, 0, 0);
        }

        // epilogue: C[row=quad*4+r][col=m]; cols 0..2 = rgb, col 3 = sigma
        #pragma unroll
        for (int r = 0; r < 4; ++r) {
            int srow = (quad << 2) + r;
            int s = (tile << 4) + srow;
            int mk = __shfl(maskS, (lane & 48) + srow, 64);
            float v = acc[r];
            if (s < NSAMP) {
                if (m == 3) {
                    float sg = mk ? fmaxf(v, 0.f) : 0.f;
                    float al = 1.f - __expf(-sg * dist);
                    out_alpha[ray * NSAMP + s] = al;     // exact fp32 output
                    alphaL[s] = __float2bfloat16(al);
                } else if (m < 3) {
                    float rv = mk ? (1.f / (1.f + __expf(-v))) : 0.5f;
                    rgbL[s * 3 + m] = __float2bfloat16(rv);
                }
            }
        }
    }

    __syncthreads();

    // ---- phase 2: transmittance scan + composite (wave 0 only) ----
    if (tid < 64) {
        int sA = tid * 12;
        int sB = min(sA + 12, NSAMP);
        float prod = 1.f;
        for (int s = sA; s < sB; ++s)
            prod *= (1.f - __bfloat162float(alphaL[s]) + 1e-10f);

        float incl = prod;
        #pragma unroll
        for (int off = 1; off < 64; off <<= 1) {
            float v = __shfl_up(incl, off, 64);
            if (tid >= off) incl *= v;
        }
        float excl = __shfl_up(incl, 1, 64);
        if (tid == 0) excl = 1.f;

        float trans = excl;
        float c0 = 0.f, c1 = 0.f, c2 = 0.f, acc = 0.f, dep = 0.f;
        for (int s = sA; s < sB; ++s) {
            float a = __bfloat162float(alphaL[s]);
            float wgt = a * trans;
            c0 += wgt * __bfloat162float(rgbL[s * 3 + 0]);
            c1 += wgt * __bfloat162float(rgbL[s * 3 + 1]);
            c2 += wgt * __bfloat162float(rgbL[s * 3 + 2]);
            acc += wgt;
            dep += wgt * (start + (float)s * STEPF);
            trans *= (1.f - a + 1e-10f);
        }
        #pragma unroll
        for (int off = 1; off < 64; off <<= 1) {
            c0  += __shfl_xor(c0, off, 64);
            c1  += __shfl_xor(c1, off, 64);
            c2  += __shfl_xor(c2, off, 64);
            acc += __shfl_xor(acc, off, 64);
            dep += __shfl_xor(dep, off, 64);
        }
        if (tid == 0) {
            float bg = 1.f - acc;
            out_rgb[ray * 3 + 0] = c0 + bg;
            out_rgb[ray * 3 + 1] = c1 + bg;
            out_rgb[ray * 3 + 2] = c2 + bg;
            out_depth[ray] = dep;
        }
    }
}

extern "C" void kernel_launch(void* const* d_in, const int* in_sizes, int n_in,
                              void* d_out, int out_size, void* d_ws, size_t ws_size,
                              hipStream_t stream) {
    const float* rays_o = (const float*)d_in[0];
    const float* rays_d = (const float*)d_in[1];
    const float* grid   = (const float*)d_in[2];
    const float* atoms  = (const float*)d_in[3];
    float* out = (float*)d_out;
    hipLaunchKernelGGL(plenoxels_fwd, dim3(BATCH), dim3(256), 0, stream,
                       rays_o, rays_d, grid, atoms, out);
}

// Round 5
// 124.360 us; speedup vs baseline: 1.2375x; 1.2375x over previous
//
#include <hip/hip_runtime.h>
#include <hip/hip_bf16.h>

#define RADIUS_F 1.3f
#define NSAMP 767
#define STEPF 0.01015625f   // RADIUS*2/COARSE/FINE/2
#define BATCH 1024

typedef __attribute__((ext_vector_type(8))) short short8;
typedef __attribute__((ext_vector_type(4))) float floatx4;

static __device__ __forceinline__ unsigned pkbf(float a, float b) {
    union { __hip_bfloat162 h; unsigned u; } cvt;
    cvt.h = __float22bfloat162_rn(make_float2(a, b));
    return cvt.u;
}

// sum over the 4-lane coset {i, i^4, i^8, i^12} inside each row of 16,
// via DPP row rotates (VALU pipe, no LDS)
static __device__ __forceinline__ float coset4_sum(float p) {
    int q4 = __builtin_amdgcn_update_dpp(0, __float_as_int(p), 0x124, 0xf, 0xf, true); // row_ror:4
    p = p + __int_as_float(q4);
    int q8 = __builtin_amdgcn_update_dpp(0, __float_as_int(p), 0x128, 0xf, 0xf, true); // row_ror:8
    return p + __int_as_float(q8);
}

__launch_bounds__(256, 2)
__global__ void plenoxels_fwd(const float* __restrict__ rays_o,
                              const float* __restrict__ rays_d,
                              const float* __restrict__ grid,
                              const float* __restrict__ atoms,
                              float* __restrict__ out)
{
    // LDS: 4096 (B'') + 3072 (W tables) + 1536 (alpha) + 4608 (rgb) = 13312 B
    __shared__ __align__(16) __hip_bfloat16 BpL[32 * 64];   // Bp[col][a], col = 4f+c
    __shared__ __align__(16) float WL[4][16 * 12];          // per-wave W[sample][f] table
    __shared__ __align__(16) __hip_bfloat16 alphaL[768];
    __shared__ __align__(16) __hip_bfloat16 rgbL[768 * 3];

    const int tid  = threadIdx.x;
    const int ray  = blockIdx.x;
    const int lane = tid & 63;
    const int w    = tid >> 6;
    const int m    = lane & 15;   // A row (sample) / B col / C col
    const int quad = lane >> 4;

    // ---- per-ray constants ----
    const float ox = rays_o[ray * 3 + 0], oy = rays_o[ray * 3 + 1], oz = rays_o[ray * 3 + 2];
    const float dx = rays_d[ray * 3 + 0], dy = rays_d[ray * 3 + 1], dz = rays_d[ray * 3 + 2];

    float start;
    {
        float a0 = (RADIUS_F - ox) / dx, b0 = (-RADIUS_F - ox) / dx;
        float a1 = (RADIUS_F - oy) / dy, b1 = (-RADIUS_F - oy) / dy;
        float a2 = (RADIUS_F - oz) / dz, b2 = (-RADIUS_F - oz) / dz;
        start = fmaxf(fminf(a0, b0), fmaxf(fminf(a1, b1), fminf(a2, b2)));
    }
    const float dnorm = sqrtf(dx * dx + dy * dy + dz * dz);
    const float dist = STEPF * dnorm;

    float shm[9];
    {
        float inv = 1.0f / dnorm;
        float nx = dx * inv, ny = dy * inv, nz = dz * inv;
        shm[0] = 0.28209479177387814f;
        shm[1] = -0.4886025119029199f * ny;
        shm[2] = 0.4886025119029199f * nz;
        shm[3] = -0.4886025119029199f * nx;
        shm[4] = 1.0925484305920792f * nx * ny;
        shm[5] = -1.0925484305920792f * ny * nz;
        shm[6] = 0.31539156525252005f * (2.f * nz * nz - nx * nx - ny * ny);
        shm[7] = -1.0925484305920792f * nx * nz;
        shm[8] = 0.5462742152960396f * (nx * nx - ny * ny);
    }

    // ---- build B''[a][col] = SH-contracted atoms, stored Bp[col][a] ----
    // col = 4f+c: c<3 -> sum_i atoms[f][a][9c+i]*shm[i]; c==3 -> atoms[f][a][27]
    for (int idx = tid; idx < 2048; idx += 256) {
        int col = idx >> 6, a = idx & 63;       // one col per wave per sweep: uniform branch
        int f = col >> 2, c = col & 3;
        const float* base = atoms + (f * 64 + a) * 28;
        float sv;
        if (c == 3) sv = base[27];
        else {
            sv = 0.f;
            #pragma unroll
            for (int i = 0; i < 9; ++i) sv = fmaf(base[c * 9 + i], shm[i], sv);
        }
        BpL[col * 64 + a] = __float2bfloat16(sv);
    }
    __syncthreads();

    // ---- B-fragments (tile-invariant): step s consumes a = 16*quad + 8s + j ----
    short8 bq00, bq01, bq10, bq11;
    {
        const short* bs = (const short*)BpL;
        const short* p0 = bs + m * 64 + (quad << 4);
        bq00 = *(const short8*)(p0);
        bq01 = *(const short8*)(p0 + 8);
        const short* p1 = bs + (16 + m) * 64 + (quad << 4);
        bq10 = *(const short8*)(p1);
        bq11 = *(const short8*)(p1 + 8);
    }

    float* out_rgb   = out;
    float* out_alpha = out + BATCH * 3;
    float* out_depth = out + BATCH * 3 + BATCH * NSAMP;
    const float4* g4 = (const float4*)grid;

    // geometry; trilinear fine weights with inclusion mask folded in (masked -> W=0)
    auto geom = [&](int s, float4& WA, float4& WB, int& clin) {
        float tr = start + (float)s * STEPF;
        float px = ox + tr * dx, py = oy + tr * dy, pz = oz + tr * dz;
        int mask = (px > -RADIUS_F) & (px < RADIUS_F) &
                   (py > -RADIUS_F) & (py < RADIUS_F) &
                   (pz > -RADIUS_F) & (pz < RADIUS_F);
        float maskf = mask ? 1.f : 0.f;
        const float sc = 1.0f / (2.0f * RADIUS_F);
        float qx = fminf(fmaxf((px + RADIUS_F) * sc, 0.f), 1.0f - 1e-6f);
        float qy = fminf(fmaxf((py + RADIUS_F) * sc, 0.f), 1.0f - 1e-6f);
        float qz = fminf(fmaxf((pz + RADIUS_F) * sc, 0.f), 1.0f - 1e-6f);
        float pcx = qx * 64.f, pcy = qy * 64.f, pcz = qz * 64.f;
        float cx = fminf(floorf(pcx), 63.f);
        float cy = fminf(floorf(pcy), 63.f);
        float cz = fminf(floorf(pcz), 63.f);
        float lx = pcx - cx, ly = pcy - cy, lz = pcz - cz;
        clin = (((int)cx * 64) + (int)cy) * 64 + (int)cz;
        float xw0, xw1, yw0, yw1, zw0, zw1;
        {
            float u = lx * 2.f - 0.5f, fF = floorf(u), t = u - fF;
            xw0 = (fF < 0.f) ? 1.f : ((fF > 0.f) ? 0.f : 1.f - t);
            xw1 = (fF < 0.f) ? 0.f : ((fF > 0.f) ? 1.f : t);
        }
        {
            float u = ly * 2.f - 0.5f, fF = floorf(u), t = u - fF;
            yw0 = (fF < 0.f) ? 1.f : ((fF > 0.f) ? 0.f : 1.f - t);
            yw1 = (fF < 0.f) ? 0.f : ((fF > 0.f) ? 1.f : t);
        }
        {
            float u = lz * 2.f - 0.5f, fF = floorf(u), t = u - fF;
            zw0 = (fF < 0.f) ? 1.f : ((fF > 0.f) ? 0.f : 1.f - t);
            zw1 = (fF < 0.f) ? 0.f : ((fF > 0.f) ? 1.f : t);
        }
        xw0 *= maskf; xw1 *= maskf;           // fold mask: W=0 => sigma=0, rgb pre-act=0
        WA = make_float4(xw0 * yw0 * zw0, xw0 * yw0 * zw1, xw0 * yw1 * zw0, xw0 * yw1 * zw1);
        WB = make_float4(xw1 * yw0 * zw0, xw1 * yw0 * zw1, xw1 * yw1 * zw0, xw1 * yw1 * zw1);
    };

    // ---- software-pipelined tile loop ----
    float4 WAc, WBc; int clinC;
    geom(w * 192 + m, WAc, WBc, clinC);
    float4 cv0, cv1, cv2, cv3;
    {
        const float4* gp = g4 + (clinC << 4) + (quad << 2);
        cv0 = gp[0]; cv1 = gp[1]; cv2 = gp[2]; cv3 = gp[3];
    }

    for (int t = 0; t < 12; ++t) {
        const int tile = w * 12 + t;

        // publish current tile's W to the per-wave LDS table (quad-0 lanes)
        if (quad == 0) {
            float* wrow = &WL[w][m * 12];
            *(float4*)(wrow)     = WAc;
            *(float4*)(wrow + 4) = WBc;
        }

        // A-frags: raw coeff, bf16 (step s uses a = 16*quad + 8s + j)
        union { unsigned u[4]; short8 s; } a0, a1;
        a0.u[0] = pkbf(cv0.x, cv0.y); a0.u[1] = pkbf(cv0.z, cv0.w);
        a0.u[2] = pkbf(cv1.x, cv1.y); a0.u[3] = pkbf(cv1.z, cv1.w);
        a1.u[0] = pkbf(cv2.x, cv2.y); a1.u[1] = pkbf(cv2.z, cv2.w);
        a1.u[2] = pkbf(cv3.x, cv3.y); a1.u[3] = pkbf(cv3.z, cv3.w);

        // prefetch next tile's geometry + coeff gather
        if (t < 11) {
            geom(w * 192 + (t + 1) * 16 + m, WAc, WBc, clinC);
            const float4* gp = g4 + (clinC << 4) + (quad << 2);
            cv0 = gp[0]; cv1 = gp[1]; cv2 = gp[2]; cv3 = gp[3];
        }

        // stage 1: proj = Coeff(16x64) x B''(64x32), two 16-col tiles
        floatx4 acc0 = {0.f, 0.f, 0.f, 0.f};
        floatx4 acc1 = {0.f, 0.f, 0.f, 0.f};
        acc0 = __builtin_amdgcn_mfma_f32_16x16x32_bf16(a0.s, bq00, acc0, 0, 0, 0);
        acc0 = __builtin_amdgcn_mfma_f32_16x16x32_bf16(a1.s, bq01, acc0, 0, 0, 0);
        acc1 = __builtin_amdgcn_mfma_f32_16x16x32_bf16(a0.s, bq10, acc1, 0, 0, 0);
        acc1 = __builtin_amdgcn_mfma_f32_16x16x32_bf16(a1.s, bq11, acc1, 0, 0, 0);

        // stage 2: out[s][c] = sum_f W[s][f] * proj[s][4f+c]
        // lane (m,quad) holds proj rows 4q+r, f = m>>2 (acc0) and 4+(m>>2) (acc1), c = m&3
        const int f0 = m >> 2;
        #pragma unroll
        for (int r = 0; r < 4; ++r) {
            const float* wrow = &WL[w][((quad << 2) + r) * 12];
            float wA = wrow[f0];
            float wB = wrow[4 + f0];
            float p = wA * acc0[r] + wB * acc1[r];
            p = coset4_sum(p);                 // reduce over f (lanes m, m^4, m^8, m^12)
            int s = (tile << 4) + (quad << 2) + r;
            if (s < NSAMP) {
                if (m == 3) {                  // c==3: sigma channel
                    float al = 1.f - __expf(-fmaxf(p, 0.f) * dist);
                    out_alpha[ray * NSAMP + s] = al;   // exact fp32 output
                    alphaL[s] = __float2bfloat16(al);
                } else if (m < 3) {            // c<3: rgb channels
                    rgbL[s * 3 + m] = __float2bfloat16(1.f / (1.f + __expf(-p)));
                }
            }
        }
    }

    __syncthreads();

    // ---- phase 2: transmittance scan + composite (wave 0 only) ----
    if (tid < 64) {
        int sA = tid * 12;
        int sB = min(sA + 12, NSAMP);
        float prod = 1.f;
        for (int s = sA; s < sB; ++s)
            prod *= (1.f - __bfloat162float(alphaL[s]) + 1e-10f);

        float incl = prod;
        #pragma unroll
        for (int off = 1; off < 64; off <<= 1) {
            float v = __shfl_up(incl, off, 64);
            if (tid >= off) incl *= v;
        }
        float excl = __shfl_up(incl, 1, 64);
        if (tid == 0) excl = 1.f;

        float trans = excl;
        float c0 = 0.f, c1 = 0.f, c2 = 0.f, acc = 0.f, dep = 0.f;
        for (int s = sA; s < sB; ++s) {
            float a = __bfloat162float(alphaL[s]);
            float wgt = a * trans;
            c0 += wgt * __bfloat162float(rgbL[s * 3 + 0]);
            c1 += wgt * __bfloat162float(rgbL[s * 3 + 1]);
            c2 += wgt * __bfloat162float(rgbL[s * 3 + 2]);
            acc += wgt;
            dep += wgt * (start + (float)s * STEPF);
            trans *= (1.f - a + 1e-10f);
        }
        #pragma unroll
        for (int off = 1; off < 64; off <<= 1) {
            c0  += __shfl_xor(c0, off, 64);
            c1  += __shfl_xor(c1, off, 64);
            c2  += __shfl_xor(c2, off, 64);
            acc += __shfl_xor(acc, off, 64);
            dep += __shfl_xor(dep, off, 64);
        }
        if (tid == 0) {
            float bg = 1.f - acc;
            out_rgb[ray * 3 + 0] = c0 + bg;
            out_rgb[ray * 3 + 1] = c1 + bg;
            out_rgb[ray * 3 + 2] = c2 + bg;
            out_depth[ray] = dep;
        }
    }
}

extern "C" void kernel_launch(void* const* d_in, const int* in_sizes, int n_in,
                              void* d_out, int out_size, void* d_ws, size_t ws_size,
                              hipStream_t stream) {
    const float* rays_o = (const float*)d_in[0];
    const float* rays_d = (const float*)d_in[1];
    const float* grid   = (const float*)d_in[2];
    const float* atoms  = (const float*)d_in[3];
    float* out = (float*)d_out;
    hipLaunchKernelGGL(plenoxels_fwd, dim3(BATCH), dim3(256), 0, stream,
                       rays_o, rays_d, grid, atoms, out);
}

// Round 6
// 123.552 us; speedup vs baseline: 1.2456x; 1.0065x over previous
//
#include <hip/hip_runtime.h>
#include <hip/hip_bf16.h>

#define RADIUS_F 1.3f
#define NSAMP 767
#define STEPF 0.01015625f   // RADIUS*2/COARSE/FINE/2
#define BATCH 1024
#define NWAVES 8            // waves per block (one block = one ray)
#define TPW 6               // tiles of 16 samples per wave (48 total = 768 slots)

typedef __attribute__((ext_vector_type(8))) short short8;
typedef __attribute__((ext_vector_type(4))) float floatx4;

static __device__ __forceinline__ unsigned pkbf(float a, float b) {
    union { __hip_bfloat162 h; unsigned u; } cvt;
    cvt.h = __float22bfloat162_rn(make_float2(a, b));
    return cvt.u;
}

// sum over the 4-lane coset {i, i^4, i^8, i^12} inside each row of 16,
// via DPP row rotates (VALU pipe, no LDS)
static __device__ __forceinline__ float coset4_sum(float p) {
    int q4 = __builtin_amdgcn_update_dpp(0, __float_as_int(p), 0x124, 0xf, 0xf, true); // row_ror:4
    p = p + __int_as_float(q4);
    int q8 = __builtin_amdgcn_update_dpp(0, __float_as_int(p), 0x128, 0xf, 0xf, true); // row_ror:8
    return p + __int_as_float(q8);
}

__launch_bounds__(512, 2)
__global__ void plenoxels_fwd(const float* __restrict__ rays_o,
                              const float* __restrict__ rays_d,
                              const float* __restrict__ grid,
                              const float* __restrict__ atoms,
                              float* __restrict__ out)
{
    // LDS: 4096 (B'') + 6144 (W tables) + 1536 (alpha) + 4608 (rgb) = 16384 B
    __shared__ __align__(16) __hip_bfloat16 BpL[32 * 64];   // Bp[col][a], col = 4f+c
    __shared__ __align__(16) float WL[NWAVES][16 * 12];     // per-wave W[sample][f] table
    __shared__ __align__(16) __hip_bfloat16 alphaL[768];
    __shared__ __align__(16) __hip_bfloat16 rgbL[768 * 3];

    const int tid  = threadIdx.x;
    const int ray  = blockIdx.x;
    const int lane = tid & 63;
    const int w    = tid >> 6;
    const int m    = lane & 15;   // A row (sample) / B col / C col
    const int quad = lane >> 4;

    // ---- per-ray constants ----
    const float ox = rays_o[ray * 3 + 0], oy = rays_o[ray * 3 + 1], oz = rays_o[ray * 3 + 2];
    const float dx = rays_d[ray * 3 + 0], dy = rays_d[ray * 3 + 1], dz = rays_d[ray * 3 + 2];

    float start;
    {
        float a0 = (RADIUS_F - ox) / dx, b0 = (-RADIUS_F - ox) / dx;
        float a1 = (RADIUS_F - oy) / dy, b1 = (-RADIUS_F - oy) / dy;
        float a2 = (RADIUS_F - oz) / dz, b2 = (-RADIUS_F - oz) / dz;
        start = fmaxf(fminf(a0, b0), fmaxf(fminf(a1, b1), fminf(a2, b2)));
    }
    const float dnorm = sqrtf(dx * dx + dy * dy + dz * dz);
    const float dist = STEPF * dnorm;

    float shm[9];
    {
        float inv = 1.0f / dnorm;
        float nx = dx * inv, ny = dy * inv, nz = dz * inv;
        shm[0] = 0.28209479177387814f;
        shm[1] = -0.4886025119029199f * ny;
        shm[2] = 0.4886025119029199f * nz;
        shm[3] = -0.4886025119029199f * nx;
        shm[4] = 1.0925484305920792f * nx * ny;
        shm[5] = -1.0925484305920792f * ny * nz;
        shm[6] = 0.31539156525252005f * (2.f * nz * nz - nx * nx - ny * ny);
        shm[7] = -1.0925484305920792f * nx * nz;
        shm[8] = 0.5462742152960396f * (nx * nx - ny * ny);
    }

    // geometry; trilinear fine weights with inclusion mask folded in (masked -> W=0)
    auto geom = [&](int s, float4& WA, float4& WB, int& clin) {
        float tr = start + (float)s * STEPF;
        float px = ox + tr * dx, py = oy + tr * dy, pz = oz + tr * dz;
        int mask = (px > -RADIUS_F) & (px < RADIUS_F) &
                   (py > -RADIUS_F) & (py < RADIUS_F) &
                   (pz > -RADIUS_F) & (pz < RADIUS_F);
        float maskf = mask ? 1.f : 0.f;
        const float sc = 1.0f / (2.0f * RADIUS_F);
        float qx = fminf(fmaxf((px + RADIUS_F) * sc, 0.f), 1.0f - 1e-6f);
        float qy = fminf(fmaxf((py + RADIUS_F) * sc, 0.f), 1.0f - 1e-6f);
        float qz = fminf(fmaxf((pz + RADIUS_F) * sc, 0.f), 1.0f - 1e-6f);
        float pcx = qx * 64.f, pcy = qy * 64.f, pcz = qz * 64.f;
        float cx = fminf(floorf(pcx), 63.f);
        float cy = fminf(floorf(pcy), 63.f);
        float cz = fminf(floorf(pcz), 63.f);
        float lx = pcx - cx, ly = pcy - cy, lz = pcz - cz;
        clin = (((int)cx * 64) + (int)cy) * 64 + (int)cz;
        float xw0, xw1, yw0, yw1, zw0, zw1;
        {
            float u = lx * 2.f - 0.5f, fF = floorf(u), t = u - fF;
            xw0 = (fF < 0.f) ? 1.f : ((fF > 0.f) ? 0.f : 1.f - t);
            xw1 = (fF < 0.f) ? 0.f : ((fF > 0.f) ? 1.f : t);
        }
        {
            float u = ly * 2.f - 0.5f, fF = floorf(u), t = u - fF;
            yw0 = (fF < 0.f) ? 1.f : ((fF > 0.f) ? 0.f : 1.f - t);
            yw1 = (fF < 0.f) ? 0.f : ((fF > 0.f) ? 1.f : t);
        }
        {
            float u = lz * 2.f - 0.5f, fF = floorf(u), t = u - fF;
            zw0 = (fF < 0.f) ? 1.f : ((fF > 0.f) ? 0.f : 1.f - t);
            zw1 = (fF < 0.f) ? 0.f : ((fF > 0.f) ? 1.f : t);
        }
        xw0 *= maskf; xw1 *= maskf;           // fold mask: W=0 => sigma=0, rgb pre-act=0
        WA = make_float4(xw0 * yw0 * zw0, xw0 * yw0 * zw1, xw0 * yw1 * zw0, xw0 * yw1 * zw1);
        WB = make_float4(xw1 * yw0 * zw0, xw1 * yw0 * zw1, xw1 * yw1 * zw0, xw1 * yw1 * zw1);
    };

    const float4* g4 = (const float4*)grid;

    // ---- issue first tile's geometry + coeff gather BEFORE the B'' build,
    //      so the L2 gather latency hides under the build ----
    float4 WAc, WBc; int clinC;
    geom(w * (TPW * 16) + m, WAc, WBc, clinC);
    float4 cv0, cv1, cv2, cv3;
    {
        const float4* gp = g4 + (clinC << 4) + (quad << 2);
        cv0 = gp[0]; cv1 = gp[1]; cv2 = gp[2]; cv3 = gp[3];
    }

    // ---- build B''[a][col] = SH-contracted atoms, stored Bp[col][a] ----
    // col = 4f+c: c<3 -> sum_i atoms[f][a][9c+i]*shm[i]; c==3 -> atoms[f][a][27]
    for (int idx = tid; idx < 2048; idx += 512) {
        int col = idx >> 6, a = idx & 63;       // col uniform per wave: uniform branch
        int f = col >> 2, c = col & 3;
        const float* base = atoms + (f * 64 + a) * 28;
        float sv;
        if (c == 3) sv = base[27];
        else {
            sv = 0.f;
            #pragma unroll
            for (int i = 0; i < 9; ++i) sv = fmaf(base[c * 9 + i], shm[i], sv);
        }
        BpL[col * 64 + a] = __float2bfloat16(sv);
    }
    __syncthreads();

    // ---- B-fragments (tile-invariant): step s consumes a = 16*quad + 8s + j ----
    short8 bq00, bq01, bq10, bq11;
    {
        const short* bs = (const short*)BpL;
        const short* p0 = bs + m * 64 + (quad << 4);
        bq00 = *(const short8*)(p0);
        bq01 = *(const short8*)(p0 + 8);
        const short* p1 = bs + (16 + m) * 64 + (quad << 4);
        bq10 = *(const short8*)(p1);
        bq11 = *(const short8*)(p1 + 8);
    }

    float* out_rgb   = out;
    float* out_alpha = out + BATCH * 3;
    float* out_depth = out + BATCH * 3 + BATCH * NSAMP;

    for (int t = 0; t < TPW; ++t) {
        const int tile = w * TPW + t;

        // publish current tile's W to the per-wave LDS table (quad-0 lanes)
        if (quad == 0) {
            float* wrow = &WL[w][m * 12];
            *(float4*)(wrow)     = WAc;
            *(float4*)(wrow + 4) = WBc;
        }

        // A-frags: raw coeff, bf16 (step s uses a = 16*quad + 8s + j)
        union { unsigned u[4]; short8 s; } a0, a1;
        a0.u[0] = pkbf(cv0.x, cv0.y); a0.u[1] = pkbf(cv0.z, cv0.w);
        a0.u[2] = pkbf(cv1.x, cv1.y); a0.u[3] = pkbf(cv1.z, cv1.w);
        a1.u[0] = pkbf(cv2.x, cv2.y); a1.u[1] = pkbf(cv2.z, cv2.w);
        a1.u[2] = pkbf(cv3.x, cv3.y); a1.u[3] = pkbf(cv3.z, cv3.w);

        // prefetch next tile's geometry + coeff gather
        if (t < TPW - 1) {
            geom(w * (TPW * 16) + (t + 1) * 16 + m, WAc, WBc, clinC);
            const float4* gp = g4 + (clinC << 4) + (quad << 2);
            cv0 = gp[0]; cv1 = gp[1]; cv2 = gp[2]; cv3 = gp[3];
        }

        // stage 1: proj = Coeff(16x64) x B''(64x32), two 16-col tiles
        floatx4 acc0 = {0.f, 0.f, 0.f, 0.f};
        floatx4 acc1 = {0.f, 0.f, 0.f, 0.f};
        acc0 = __builtin_amdgcn_mfma_f32_16x16x32_bf16(a0.s, bq00, acc0, 0, 0, 0);
        acc0 = __builtin_amdgcn_mfma_f32_16x16x32_bf16(a1.s, bq01, acc0, 0, 0, 0);
        acc1 = __builtin_amdgcn_mfma_f32_16x16x32_bf16(a0.s, bq10, acc1, 0, 0, 0);
        acc1 = __builtin_amdgcn_mfma_f32_16x16x32_bf16(a1.s, bq11, acc1, 0, 0, 0);

        // stage 2: out[s][c] = sum_f W[s][f] * proj[s][4f+c]
        // lane (m,quad) holds proj rows 4q+r, f = m>>2 (acc0) and 4+(m>>2) (acc1), c = m&3
        const int f0 = m >> 2;
        #pragma unroll
        for (int r = 0; r < 4; ++r) {
            const float* wrow = &WL[w][((quad << 2) + r) * 12];
            float wA = wrow[f0];
            float wB = wrow[4 + f0];
            float p = wA * acc0[r] + wB * acc1[r];
            p = coset4_sum(p);                 // reduce over f (lanes m, m^4, m^8, m^12)
            int s = (tile << 4) + (quad << 2) + r;
            if (s < NSAMP) {
                if (m == 3) {                  // c==3: sigma channel
                    float al = 1.f - __expf(-fmaxf(p, 0.f) * dist);
                    out_alpha[ray * NSAMP + s] = al;   // exact fp32 output
                    alphaL[s] = __float2bfloat16(al);
                } else if (m < 3) {            // c<3: rgb channels
                    rgbL[s * 3 + m] = __float2bfloat16(1.f / (1.f + __expf(-p)));
                }
            }
        }
    }

    __syncthreads();

    // ---- phase 2: transmittance scan + composite (wave 0 only) ----
    if (tid < 64) {
        int sA = tid * 12;
        int sB = min(sA + 12, NSAMP);
        float prod = 1.f;
        for (int s = sA; s < sB; ++s)
            prod *= (1.f - __bfloat162float(alphaL[s]) + 1e-10f);

        float incl = prod;
        #pragma unroll
        for (int off = 1; off < 64; off <<= 1) {
            float v = __shfl_up(incl, off, 64);
            if (tid >= off) incl *= v;
        }
        float excl = __shfl_up(incl, 1, 64);
        if (tid == 0) excl = 1.f;

        float trans = excl;
        float c0 = 0.f, c1 = 0.f, c2 = 0.f, acc = 0.f, dep = 0.f;
        for (int s = sA; s < sB; ++s) {
            float a = __bfloat162float(alphaL[s]);
            float wgt = a * trans;
            c0 += wgt * __bfloat162float(rgbL[s * 3 + 0]);
            c1 += wgt * __bfloat162float(rgbL[s * 3 + 1]);
            c2 += wgt * __bfloat162float(rgbL[s * 3 + 2]);
            acc += wgt;
            dep += wgt * (start + (float)s * STEPF);
            trans *= (1.f - a + 1e-10f);
        }
        #pragma unroll
        for (int off = 1; off < 64; off <<= 1) {
            c0  += __shfl_xor(c0, off, 64);
            c1  += __shfl_xor(c1, off, 64);
            c2  += __shfl_xor(c2, off, 64);
            acc += __shfl_xor(acc, off, 64);
            dep += __shfl_xor(dep, off, 64);
        }
        if (tid == 0) {
            float bg = 1.f - acc;
            out_rgb[ray * 3 + 0] = c0 + bg;
            out_rgb[ray * 3 + 1] = c1 + bg;
            out_rgb[ray * 3 + 2] = c2 + bg;
            out_depth[ray] = dep;
        }
    }
}

extern "C" void kernel_launch(void* const* d_in, const int* in_sizes, int n_in,
                              void* d_out, int out_size, void* d_ws, size_t ws_size,
                              hipStream_t stream) {
    const float* rays_o = (const float*)d_in[0];
    const float* rays_d = (const float*)d_in[1];
    const float* grid   = (const float*)d_in[2];
    const float* atoms  = (const float*)d_in[3];
    float* out = (float*)d_out;
    hipLaunchKernelGGL(plenoxels_fwd, dim3(BATCH), dim3(512), 0, stream,
                       rays_o, rays_d, grid, atoms, out);
}